// Round 7
// baseline (137.536 us; speedup 1.0000x reference)
//
#include <hip/hip_runtime.h>

// SpatioTemporalGCN: B=64, T=12, N=1024, Ci=64, E=16, K=3, H=192, O=64
// out(b,n,:) = [l2norm(gconv) | l2norm(aconv) | l2norm(wconv)] + bias(n,:)
//
// Layout plan (r7): everything matmul-shaped is a clean m97-style GEMM with
// k-contiguous row-major operands staged via global_load_lds (no VALU repack):
//   S   = softmax(relu(E E^T))            [n][m]
//   ST  = S^T                              [j][m]   (transS, once)
//   XT  = x as [j=b*64+c][m]                        (transX, once)
//   S2  = S @ S (via ST)                   [n][m]
//   Y1E = S  @ x  -> [n][j]   (epi-coalesced)
//   Y2E = S2 @ x  -> [n][j]
//   Wall = per-node weights, fragment-interleaved [n][k-slice][o][8]

typedef __attribute__((ext_vector_type(4))) float f32x4;
typedef __attribute__((ext_vector_type(8))) short short8;

#define DEVI static __device__ __forceinline__

DEVI short f2bf(float f) {
    unsigned int x = __builtin_bit_cast(unsigned int, f);
    x = (x + 0x7FFFu + ((x >> 16) & 1u)) >> 16;  // RNE
    return (short)(unsigned short)x;
}
DEVI int swz(int row) { return ((row ^ (row >> 3)) & 7) << 3; }

DEVI f32x4 mfma16(short8 a, short8 b, f32x4 c) {
    return __builtin_amdgcn_mfma_f32_16x16x32_bf16(a, b, c, 0, 0, 0);
}

DEVI void gload16(const void* g, void* l) {
    __builtin_amdgcn_global_load_lds(
        (const __attribute__((address_space(1))) unsigned int*)g,
        (__attribute__((address_space(3))) unsigned int*)l, 16, 0, 0);
}

// ---------------- supports: S = softmax(relu(E E^T), axis=1), bf16 row-major ----------------
__global__ __launch_bounds__(256) void k_supports(const float* __restrict__ NE,
                                                  short* __restrict__ S) {
    int n = blockIdx.x, t = threadIdx.x;
    __shared__ float En[16];
    __shared__ float wsum[4];
    if (t < 16) En[t] = NE[n * 16 + t];
    __syncthreads();
    float e[4];
    float loc = 0.f;
#pragma unroll
    for (int i = 0; i < 4; ++i) {
        int m = t + 256 * i;
        const float* rp = NE + m * 16;
        float v = 0.f;
#pragma unroll
        for (int d = 0; d < 16; ++d) v += En[d] * rp[d];
        v = fmaxf(v, 0.f);
        e[i] = __expf(v);
        loc += e[i];
    }
#pragma unroll
    for (int off = 32; off; off >>= 1) loc += __shfl_xor(loc, off);
    if ((t & 63) == 0) wsum[t >> 6] = loc;
    __syncthreads();
    float inv = 1.f / (wsum[0] + wsum[1] + wsum[2] + wsum[3]);
#pragma unroll
    for (int i = 0; i < 4; ++i) S[n * 1024 + t + 256 * i] = f2bf(e[i] * inv);
}

// ---------------- pre2: transX (512) | transS (256) | B2 (64) | s_bn (16) | A2 (4) ----------------
__global__ __launch_bounds__(256) void k_pre2(
        const float* __restrict__ NE, const float* __restrict__ x,
        const float* __restrict__ xw, const float* __restrict__ adj,
        const float* __restrict__ wp, const float* __restrict__ wpa,
        const float* __restrict__ Tp, const short* __restrict__ S,
        short* __restrict__ ST, short* __restrict__ XT,
        short* __restrict__ B2, short* __restrict__ A2,
        float* __restrict__ xsp, float* __restrict__ s_bn) {
    __shared__ __align__(16) short Tbuf[64 * 136];
    __shared__ float red[16][64];
    int bid = blockIdx.x, t = threadIdx.x;
    if (bid < 512) {  // transX: b = bid>>3, m-tile = bid&7; + xsum partials
        int b = bid >> 3, m0 = (bid & 7) * 128;
        const float* xp = x + ((size_t)b * 1024 + m0) * 64;
        float4 sum4 = {0.f, 0.f, 0.f, 0.f};
        int c4 = (t & 15) * 4;
#pragma unroll
        for (int p = 0; p < 8; ++p) {
            int idx = t + 256 * p;
            int r = idx >> 4;
            float4 v = *reinterpret_cast<const float4*>(&xp[r * 64 + c4]);
            Tbuf[(c4 + 0) * 136 + r] = f2bf(v.x);
            Tbuf[(c4 + 1) * 136 + r] = f2bf(v.y);
            Tbuf[(c4 + 2) * 136 + r] = f2bf(v.z);
            Tbuf[(c4 + 3) * 136 + r] = f2bf(v.w);
            sum4.x += v.x; sum4.y += v.y; sum4.z += v.z; sum4.w += v.w;
        }
        int g = t >> 4;
        red[g][c4 + 0] = sum4.x; red[g][c4 + 1] = sum4.y;
        red[g][c4 + 2] = sum4.z; red[g][c4 + 3] = sum4.w;
        __syncthreads();
#pragma unroll
        for (int p = 0; p < 4; ++p) {
            int idx = t + 256 * p;
            int c = idx >> 4, q = idx & 15;
            *reinterpret_cast<short8*>(&XT[((size_t)b * 64 + c) * 1024 + m0 + q * 8]) =
                *reinterpret_cast<const short8*>(&Tbuf[c * 136 + q * 8]);
        }
        if (t < 64) {
            float tot = 0.f;
#pragma unroll
            for (int gg = 0; gg < 16; ++gg) tot += red[gg][t];
            xsp[((size_t)b * 8 + (bid & 7)) * 64 + t] = tot;
        }
    } else if (bid < 768) {  // transS: 64x64 tile (bi,bj), full 64 rows
        int idx = bid - 512, bi = idx >> 4, bj = idx & 15;
        int c8 = (t & 7) * 8;
#pragma unroll
        for (int p = 0; p < 2; ++p) {
            int r = (t >> 3) + 32 * p;
            short8 v = *reinterpret_cast<const short8*>(
                &S[(size_t)(bi * 64 + r) * 1024 + bj * 64 + c8]);
#pragma unroll
            for (int e = 0; e < 8; ++e) Tbuf[(c8 + e) * 64 + r] = v[e];
        }
        __syncthreads();
#pragma unroll
        for (int p = 0; p < 2; ++p) {
            int r = (t >> 3) + 32 * p;
            *reinterpret_cast<short8*>(&ST[(size_t)(bj * 64 + r) * 1024 + bi * 64 + c8]) =
                *reinterpret_cast<const short8*>(&Tbuf[r * 64 + c8]);
        }
    } else if (bid < 832) {  // B2 operand rows for o
        int o = bid - 768, j = t;
        short row[64];
        if (j < 192) {
            int kk = j >> 6, i = j & 63;
#pragma unroll
            for (int d = 0; d < 16; ++d)
                row[d] = f2bf(wp[((d * 3 + kk) * 64 + i) * 64 + o]);
#pragma unroll
            for (int k = 16; k < 64; ++k) row[k] = 0;
        } else {
            int i2 = j - 192;
#pragma unroll
            for (int k = 0; k < 16; ++k) row[k] = 0;
#pragma unroll
            for (int d = 0; d < 16; ++d)
#pragma unroll
                for (int kk = 0; kk < 3; ++kk)
                    row[16 + d * 3 + kk] = f2bf(wpa[((d * 3 + kk) * 64 + i2) * 64 + o]);
        }
        short* dst = B2 + (o * 256 + j) * 64;
#pragma unroll
        for (int q = 0; q < 8; ++q) {
            short8 v;
#pragma unroll
            for (int e2 = 0; e2 < 8; ++e2) v[e2] = row[q * 8 + e2];
            *reinterpret_cast<short8*>(dst + q * 8) = v;
        }
    } else if (bid < 848) {  // s_bn[b][n] = sum_t xw[b,t,n]*Tp[t]
        int idx = bid - 832;
        float tp[12];
#pragma unroll
        for (int i = 0; i < 12; ++i) tp[i] = Tp[i];
        for (int bb = 0; bb < 4; ++bb) {
            int b = idx * 4 + bb;
#pragma unroll
            for (int j2 = 0; j2 < 4; ++j2) {
                int nn = t + 256 * j2;
                float s = 0.f;
#pragma unroll
                for (int tt = 0; tt < 12; ++tt) s += xw[(b * 12 + tt) * 1024 + nn] * tp[tt];
                s_bn[b * 1024 + nn] = s;
            }
        }
    } else {  // A2 rows (4 blocks)
        int n = (bid - 848) * 256 + t;
        float Enr[16];
#pragma unroll
        for (int d = 0; d < 16; ++d) Enr[d] = NE[n * 16 + d];
        float dg[3];
#pragma unroll
        for (int k = 0; k < 3; ++k) dg[k] = adj[k * 1024 * 1024 + n * 1024 + n];
        short row[64];
#pragma unroll
        for (int d = 0; d < 16; ++d) row[d] = f2bf(Enr[d]);
#pragma unroll
        for (int d = 0; d < 16; ++d)
#pragma unroll
            for (int k = 0; k < 3; ++k) row[16 + d * 3 + k] = f2bf(Enr[d] * dg[k]);
        short* dst = A2 + n * 64;
#pragma unroll
        for (int q = 0; q < 8; ++q) {
            short8 v;
#pragma unroll
            for (int e2 = 0; e2 < 8; ++e2) v[e2] = row[q * 8 + e2];
            *reinterpret_cast<short8*>(dst + q * 8) = v;
        }
    }
}

// ---------------- 128x128 bf16 GEMM tile core (m97-style: global_load_lds, linear LDS) ----------------
DEVI void mm_tile(const short* __restrict__ A, const short* __restrict__ Bt,
                  short* __restrict__ C, int ldC) {
    __shared__ __align__(16) short As[128 * 64];
    __shared__ __align__(16) short Bs[128 * 64];
    int t = threadIdx.x, wid = t >> 6, lane = t & 63;
    int rsub = lane >> 3, csub = (lane & 7) * 8;
    int wm = wid & 1, wn = wid >> 1;
    int lr = lane & 15, lg = lane >> 4;
    f32x4 acc[4][4] = {};
    for (int kt = 0; kt < 16; ++kt) {
#pragma unroll
        for (int q = 0; q < 4; ++q) {
            int row = q * 32 + wid * 8;
            gload16(A + (size_t)(row + rsub) * 1024 + kt * 64 + csub, As + row * 64);
            gload16(Bt + (size_t)(row + rsub) * 1024 + kt * 64 + csub, Bs + row * 64);
        }
        __syncthreads();
#pragma unroll
        for (int ks = 0; ks < 2; ++ks) {
            int kk = ks * 32 + lg * 8;
            short8 af[4], bfv[4];
#pragma unroll
            for (int i = 0; i < 4; ++i)
                af[i] = *reinterpret_cast<const short8*>(&As[(wm * 64 + i * 16 + lr) * 64 + kk]);
#pragma unroll
            for (int i = 0; i < 4; ++i)
                bfv[i] = *reinterpret_cast<const short8*>(&Bs[(wn * 64 + i * 16 + lr) * 64 + kk]);
#pragma unroll
            for (int mf = 0; mf < 4; ++mf)
#pragma unroll
                for (int nf = 0; nf < 4; ++nf)
                    acc[mf][nf] = mfma16(af[mf], bfv[nf], acc[mf][nf]);
        }
        __syncthreads();
    }
#pragma unroll
    for (int mf = 0; mf < 4; ++mf)
#pragma unroll
        for (int nf = 0; nf < 4; ++nf)
#pragma unroll
            for (int r = 0; r < 4; ++r) {
                int g = wm * 64 + mf * 16 + lg * 4 + r;
                int j = wn * 64 + nf * 16 + lr;
                C[(size_t)g * ldC + j] = f2bf(acc[mf][nf][r]);
            }
}

// ---------------- gemmS2: S2 = S @ S (via ST); spare block finalizes xsum ----------------
__global__ __launch_bounds__(256) void k_gemmS2(const short* __restrict__ S,
                                                const short* __restrict__ ST,
                                                short* __restrict__ S2,
                                                const float* __restrict__ xsp,
                                                short* __restrict__ xs_bf) {
    int bid = blockIdx.x, t = threadIdx.x;
    if (bid == 64) {  // xs finalize: 4096 outputs
#pragma unroll
        for (int it = 0; it < 16; ++it) {
            int j = it * 256 + t;
            int b = j >> 6, c = j & 63;
            float s = 0.f;
#pragma unroll
            for (int mt = 0; mt < 8; ++mt) s += xsp[((size_t)b * 8 + mt) * 64 + c];
            xs_bf[j] = f2bf(s);
        }
        return;
    }
    int by = bid >> 3, bx = bid & 7;
    mm_tile(S + (size_t)by * 131072, ST + (size_t)bx * 131072,
            S2 + (size_t)by * 131072 + bx * 128, 1024);
}

// ---------------- gemmY: [Y1E; Y2E] = [S; S2] @ XT^T, row-major [n][j] out ----------------
__global__ __launch_bounds__(256) void k_gemmY(const short* __restrict__ S,
                                               const short* __restrict__ S2,
                                               const short* __restrict__ XT,
                                               short* __restrict__ Y1E,
                                               short* __restrict__ Y2E) {
    int bx = blockIdx.x, by = blockIdx.y;
    const short* A = (by < 8) ? (S + (size_t)by * 131072)
                              : (S2 + (size_t)(by - 8) * 131072);
    short* C = ((by < 8) ? Y1E : Y2E) + (size_t)(by & 7) * 128 * 4096 + bx * 128;
    mm_tile(A, XT + (size_t)bx * 131072, C, 4096);
}

// ---------------- Wall = A2 (1024x64) @ B2^T, fragment-interleaved ----------------
// Wall[n*16384 + (j>>3)*512 + o*8 + (j&7)]  (j = epi-k 0..255, o = 0..63)
__global__ __launch_bounds__(256) void k_gemm_w(const short* __restrict__ A2,
                                                const short* __restrict__ B2,
                                                short* __restrict__ Wall) {
    int bx = blockIdx.x, by = blockIdx.y, t = threadIdx.x;
    __shared__ __align__(16) short As[128 * 64];
    __shared__ __align__(16) short Bs[128 * 64];
#pragma unroll
    for (int i = 0; i < 4; ++i) {
        int slot = t + 256 * i;
        int row = slot >> 3, k8 = slot & 7;
        int sw = swz(row);
        short8 va = *reinterpret_cast<const short8*>(A2 + (by * 128 + row) * 64 + k8 * 8);
        *reinterpret_cast<short8*>(&As[row * 64 + ((k8 * 8) ^ sw)]) = va;
        short8 vb = *reinterpret_cast<const short8*>(B2 + (bx * 128 + row) * 64 + k8 * 8);
        *reinterpret_cast<short8*>(&Bs[row * 64 + ((k8 * 8) ^ sw)]) = vb;
    }
    __syncthreads();
    int w = t >> 6, l = t & 63;
    int wm = w & 1, wn = w >> 1;
    int lr = l & 15, lg = l >> 4;
    f32x4 acc[4][4] = {};
#pragma unroll
    for (int ks = 0; ks < 2; ++ks) {
        int kk = ks * 32 + lg * 8;
        short8 af[4], bfr[4];
#pragma unroll
        for (int mf = 0; mf < 4; ++mf) {
            int row = wm * 64 + mf * 16 + lr;
            af[mf] = *reinterpret_cast<const short8*>(&As[row * 64 + (kk ^ swz(row))]);
        }
#pragma unroll
        for (int nf = 0; nf < 4; ++nf) {
            int row = wn * 64 + nf * 16 + lr;
            bfr[nf] = *reinterpret_cast<const short8*>(&Bs[row * 64 + (kk ^ swz(row))]);
        }
#pragma unroll
        for (int mf = 0; mf < 4; ++mf)
#pragma unroll
            for (int nf = 0; nf < 4; ++nf)
                acc[mf][nf] = mfma16(af[mf], bfr[nf], acc[mf][nf]);
    }
#pragma unroll
    for (int mf = 0; mf < 4; ++mf)
#pragma unroll
        for (int nf = 0; nf < 4; ++nf)
#pragma unroll
            for (int r = 0; r < 4; ++r) {
                int row = by * 128 + wm * 64 + mf * 16 + lg * 4 + r;
                int col = bx * 128 + wn * 64 + nf * 16 + lr;
                int o = col >> 8, j = col & 255;
                Wall[(size_t)row * 16384 + (size_t)(j >> 3) * 512 + o * 8 + (j & 7)] =
                    f2bf(acc[mf][nf][r]);
            }
}

// ---------------- epilogue: register-prefetch per-node MFMA (M=64 b, N=64 o, K=256) ----------------
__global__ __launch_bounds__(256) void k_epi(
        const float* __restrict__ x, const short* __restrict__ Y1E,
        const short* __restrict__ Y2E, const short* __restrict__ xs_bf,
        const float* __restrict__ s_bn, const short* __restrict__ Wall,
        const float* __restrict__ NE, const float* __restrict__ bp,
        const float* __restrict__ wwin, float* __restrict__ out) {
    int n = blockIdx.x, t = threadIdx.x;
    __shared__ float E_l[16];
    __shared__ float bias_l[192];
    __shared__ float ww_l[64];
    __shared__ float sq_l[2][2][64];
    __shared__ float wwn_l;
    if (t < 16) E_l[t] = NE[n * 16 + t];
    int w = t >> 6, l = t & 63;
    int wm = w & 1, wn = w >> 1;
    int lr = l & 15, lg = l >> 4;
    // ---- issue ALL main-loop loads up front ----
    short8 wfk[8][2];
#pragma unroll
    for (int ks = 0; ks < 8; ++ks)
#pragma unroll
        for (int nf = 0; nf < 2; ++nf) {
            int o = wn * 32 + nf * 16 + lr;
            wfk[ks][nf] = *reinterpret_cast<const short8*>(
                &Wall[(size_t)n * 16384 + (size_t)(ks * 4 + lg) * 512 + o * 8]);
        }
    short8 af[8][2];
#pragma unroll
    for (int ks = 0; ks < 8; ++ks)
#pragma unroll
        for (int mf = 0; mf < 2; ++mf) {
            int b = wm * 32 + mf * 16 + lr;
            int k0 = ks * 32 + lg * 8;
            if (ks < 2) {
                const float4* p =
                    reinterpret_cast<const float4*>(&x[((size_t)b * 1024 + n) * 64 + k0]);
                float4 p0 = p[0], p1 = p[1];
                short8 v;
                v[0] = f2bf(p0.x); v[1] = f2bf(p0.y); v[2] = f2bf(p0.z); v[3] = f2bf(p0.w);
                v[4] = f2bf(p1.x); v[5] = f2bf(p1.y); v[6] = f2bf(p1.z); v[7] = f2bf(p1.w);
                af[ks][mf] = v;
            } else if (ks < 4) {
                af[ks][mf] = *reinterpret_cast<const short8*>(
                    &Y1E[(size_t)n * 4096 + b * 64 + (k0 - 64)]);
            } else if (ks < 6) {
                af[ks][mf] = *reinterpret_cast<const short8*>(
                    &Y2E[(size_t)n * 4096 + b * 64 + (k0 - 128)]);
            } else {
                af[ks][mf] = *reinterpret_cast<const short8*>(&xs_bf[b * 64 + (k0 - 192)]);
            }
        }
    __syncthreads();
    if (t < 192) {
        float s = 0.f;
#pragma unroll
        for (int d = 0; d < 16; ++d) s += E_l[d] * bp[d * 192 + t];
        bias_l[t] = s;
    } else {
        int o = t - 192;
        float s = 0.f;
#pragma unroll
        for (int d = 0; d < 16; ++d) s += E_l[d] * wwin[d * 64 + o];
        ww_l[o] = s;
    }
    __syncthreads();
    if (t < 64) {  // ||ww||
        float v = ww_l[t];
        float s2 = v * v;
#pragma unroll
        for (int off = 32; off; off >>= 1) s2 += __shfl_xor(s2, off);
        if (t == 0) wwn_l = sqrtf(s2);
    }
    // ---- MFMA burst ----
    f32x4 accg[2][2] = {};
    f32x4 acca[2][2] = {};
#pragma unroll
    for (int ks = 0; ks < 8; ++ks)
#pragma unroll
        for (int mf = 0; mf < 2; ++mf)
#pragma unroll
            for (int nf = 0; nf < 2; ++nf) {
                if (ks < 6) accg[mf][nf] = mfma16(af[ks][mf], wfk[ks][nf], accg[mf][nf]);
                else        acca[mf][nf] = mfma16(af[ks][mf], wfk[ks][nf], acca[mf][nf]);
            }
#pragma unroll
    for (int mf = 0; mf < 2; ++mf)
#pragma unroll
        for (int r = 0; r < 4; ++r) {
            float sg = accg[mf][0][r] * accg[mf][0][r] + accg[mf][1][r] * accg[mf][1][r];
            float sa = acca[mf][0][r] * acca[mf][0][r] + acca[mf][1][r] * acca[mf][1][r];
#pragma unroll
            for (int off = 1; off < 16; off <<= 1) {
                sg += __shfl_xor(sg, off);
                sa += __shfl_xor(sa, off);
            }
            if (lr == 0) {
                int b = wm * 32 + mf * 16 + lg * 4 + r;
                sq_l[0][wn][b] = sg;
                sq_l[1][wn][b] = sa;
            }
        }
    __syncthreads();
#pragma unroll
    for (int mf = 0; mf < 2; ++mf)
#pragma unroll
        for (int r = 0; r < 4; ++r) {
            int b = wm * 32 + mf * 16 + lg * 4 + r;
            float ig = 1.f / fmaxf(sqrtf(sq_l[0][0][b] + sq_l[0][1][b]), 1e-12f);
            float ia = 1.f / fmaxf(sqrtf(sq_l[1][0][b] + sq_l[1][1][b]), 1e-12f);
            float* po = out + ((size_t)b * 1024 + n) * 192;
#pragma unroll
            for (int nf = 0; nf < 2; ++nf) {
                int o = wn * 32 + nf * 16 + lr;
                po[o]      = accg[mf][nf][r] * ig + bias_l[o];
                po[64 + o] = acca[mf][nf][r] * ia + bias_l[64 + o];
            }
        }
    // wconv
    float wwn = wwn_l;
#pragma unroll
    for (int it = 0; it < 16; ++it) {
        int b = it * 4 + (t >> 6);
        int o = t & 63;
        float s = s_bn[b * 1024 + n];
        float pre = s * ww_l[o];
        float nrm = fabsf(s) * wwn;
        out[((size_t)b * 1024 + n) * 192 + 128 + o] = pre / fmaxf(nrm, 1e-12f) + bias_l[128 + o];
    }
}

extern "C" void kernel_launch(void* const* d_in, const int* in_sizes, int n_in,
                              void* d_out, int out_size, void* d_ws, size_t ws_size,
                              hipStream_t stream) {
    const float* x    = (const float*)d_in[0];
    const float* xw   = (const float*)d_in[1];
    const float* NE   = (const float*)d_in[2];
    const float* adj  = (const float*)d_in[4];
    const float* wp   = (const float*)d_in[5];
    const float* wpa  = (const float*)d_in[6];
    const float* wwin = (const float*)d_in[7];
    const float* bp   = (const float*)d_in[8];
    const float* Tp   = (const float*)d_in[9];
    float* out = (float*)d_out;

    char* ws = (char*)d_ws;
    // Lifetimes: S/ST/S2/XT die after k_gemmY; Wall (written by k_gemm_w AFTER
    // gemmY) overlays them at 19MB. Alive at epi: Y1E, Y2E, Wall, xs/sbn.
    const size_t OFF_Y1E  = 0;           // 8 MB
    const size_t OFF_Y2E  = 8388608;     // 8 MB
    const size_t OFF_XSBF = 16777216;    // 8 KB
    const size_t OFF_XSP  = 16842752;    // 128 KB
    const size_t OFF_SBN  = 17039360;    // 256 KB
    const size_t OFF_A2   = 17301504;    // 128 KB
    const size_t OFF_B2   = 17563648;    // 2 MB (ends 19660800)
    const size_t OFF_WALL = 19922944;    // 32 MB (ends 53477376)
    const size_t OFF_S    = 19922944;    // 2 MB  } overlay, dead before gemm_w
    const size_t OFF_ST   = 22020096;    // 2 MB  }
    const size_t OFF_S2   = 24117248;    // 2 MB  }
    const size_t OFF_XT   = 26214400;    // 8 MB  } (ends 34603008)
    const size_t NEED     = 53477376;
    if (ws_size < NEED) return;  // fails validation loudly

    short* Y1E   = (short*)(ws + OFF_Y1E);
    short* Y2E   = (short*)(ws + OFF_Y2E);
    short* xs_bf = (short*)(ws + OFF_XSBF);
    float* xsp   = (float*)(ws + OFF_XSP);
    float* s_bn  = (float*)(ws + OFF_SBN);
    short* A2    = (short*)(ws + OFF_A2);
    short* B2    = (short*)(ws + OFF_B2);
    short* Wall  = (short*)(ws + OFF_WALL);
    short* S     = (short*)(ws + OFF_S);
    short* ST    = (short*)(ws + OFF_ST);
    short* S2    = (short*)(ws + OFF_S2);
    short* XT    = (short*)(ws + OFF_XT);

    k_supports<<<1024, 256, 0, stream>>>(NE, S);
    k_pre2<<<852, 256, 0, stream>>>(NE, x, xw, adj, wp, wpa, Tp, S, ST, XT, B2, A2, xsp, s_bn);
    k_gemmS2<<<65, 256, 0, stream>>>(S, ST, S2, xsp, xs_bf);
    k_gemmY<<<dim3(32, 16), 256, 0, stream>>>(S, S2, XT, Y1E, Y2E);
    k_gemm_w<<<dim3(128, 8), 256, 0, stream>>>(A2, B2, Wall);
    k_epi<<<1024, 256, 0, stream>>>(x, Y1E, Y2E, xs_bf, s_bn, Wall, NE, bp, wwin, out);
}

// Round 8
// 123.840 us; speedup vs baseline: 1.1106x; 1.1106x over previous
//
#include <hip/hip_runtime.h>

// SpatioTemporalGCN: B=64, T=12, N=1024, Ci=64, E=16, K=3, H=192, O=64
// out(b,n,:) = [l2norm(gconv) | l2norm(aconv) | l2norm(wconv)] + bias(n,:)
//
// r8 = measured-best parts: r1 gemm pipeline + r4 epi, unified Y layout [n][j=b*64+c].

typedef __attribute__((ext_vector_type(4))) float f32x4;
typedef __attribute__((ext_vector_type(8))) short short8;

#define DEVI static __device__ __forceinline__

DEVI short f2bf(float f) {
    unsigned int x = __builtin_bit_cast(unsigned int, f);
    x = (x + 0x7FFFu + ((x >> 16) & 1u)) >> 16;  // RNE
    return (short)(unsigned short)x;
}
DEVI int swz(int row) { return ((row ^ (row >> 3)) & 7) << 3; }

DEVI f32x4 mfma16(short8 a, short8 b, f32x4 c) {
    return __builtin_amdgcn_mfma_f32_16x16x32_bf16(a, b, c, 0, 0, 0);
}

DEVI void gload16(const void* g, void* l) {
    __builtin_amdgcn_global_load_lds(
        (const __attribute__((address_space(1))) unsigned int*)g,
        (__attribute__((address_space(3))) unsigned int*)l, 16, 0, 0);
}

// ---------------- supports: S = softmax(relu(E E^T), axis=1), bf16 row-major ----------------
__global__ __launch_bounds__(256) void k_supports(const float* __restrict__ NE,
                                                  short* __restrict__ S) {
    int n = blockIdx.x, t = threadIdx.x;
    __shared__ float En[16];
    __shared__ float wsum[4];
    if (t < 16) En[t] = NE[n * 16 + t];
    __syncthreads();
    float e[4];
    float loc = 0.f;
#pragma unroll
    for (int i = 0; i < 4; ++i) {
        int m = t + 256 * i;
        const float* rp = NE + m * 16;
        float v = 0.f;
#pragma unroll
        for (int d = 0; d < 16; ++d) v += En[d] * rp[d];
        v = fmaxf(v, 0.f);
        e[i] = __expf(v);
        loc += e[i];
    }
#pragma unroll
    for (int off = 32; off; off >>= 1) loc += __shfl_xor(loc, off);
    if ((t & 63) == 0) wsum[t >> 6] = loc;
    __syncthreads();
    float inv = 1.f / (wsum[0] + wsum[1] + wsum[2] + wsum[3]);
#pragma unroll
    for (int i = 0; i < 4; ++i) S[n * 1024 + t + 256 * i] = f2bf(e[i] * inv);
}

// ---------------- misc prep: B2 rows, xsum partials, s_bn, A2 rows (r1 structure) ----------------
__global__ __launch_bounds__(256) void k_small(
        const float* __restrict__ x, const float* __restrict__ xw,
        const float* __restrict__ NE, const float* __restrict__ adj,
        const float* __restrict__ wp, const float* __restrict__ wpa,
        const float* __restrict__ Tp,
        short* __restrict__ B2, short* __restrict__ A2,
        float* __restrict__ xsp, float* __restrict__ s_bn) {
    __shared__ float red[4][64];
    int bid = blockIdx.x, t = threadIdx.x;
    if (bid < 64) {  // B2 operand rows for o = bid
        int o = bid, j = t;
        short row[64];
        if (j < 192) {
            int kk = j >> 6, i = j & 63;
#pragma unroll
            for (int d = 0; d < 16; ++d)
                row[d] = f2bf(wp[((d * 3 + kk) * 64 + i) * 64 + o]);
#pragma unroll
            for (int k = 16; k < 64; ++k) row[k] = 0;
        } else {
            int i2 = j - 192;
#pragma unroll
            for (int k = 0; k < 16; ++k) row[k] = 0;
#pragma unroll
            for (int d = 0; d < 16; ++d)
#pragma unroll
                for (int kk = 0; kk < 3; ++kk)
                    row[16 + d * 3 + kk] = f2bf(wpa[((d * 3 + kk) * 64 + i2) * 64 + o]);
        }
        short* dst = B2 + (o * 256 + j) * 64;
#pragma unroll
        for (int q = 0; q < 8; ++q) {
            short8 v;
#pragma unroll
            for (int e2 = 0; e2 < 8; ++e2) v[e2] = row[q * 8 + e2];
            *reinterpret_cast<short8*>(dst + q * 8) = v;
        }
    } else if (bid < 320) {  // xsum partials: xsp[(b*4+mq)*64+c]
        int idx = bid - 64, b = idx >> 2, mq = idx & 3;
        int c = t & 63, q2 = t >> 6;
        int m0 = mq * 256 + q2 * 64;
        float s = 0.f;
        for (int mm = 0; mm < 64; ++mm) s += x[((size_t)b * 1024 + m0 + mm) * 64 + c];
        red[q2][c] = s;
        __syncthreads();
        if (t < 64) xsp[(b * 4 + mq) * 64 + t] = red[0][t] + red[1][t] + red[2][t] + red[3][t];
    } else if (bid < 336) {  // s_bn[b][n] = sum_t xw[b,t,n]*Tp[t]
        int idx = bid - 320;
        float tp[12];
#pragma unroll
        for (int i = 0; i < 12; ++i) tp[i] = Tp[i];
        for (int bb = 0; bb < 4; ++bb) {
            int b = idx * 4 + bb;
#pragma unroll
            for (int j2 = 0; j2 < 4; ++j2) {
                int nn = t + 256 * j2;
                float s = 0.f;
#pragma unroll
                for (int tt = 0; tt < 12; ++tt) s += xw[(b * 12 + tt) * 1024 + nn] * tp[tt];
                s_bn[b * 1024 + nn] = s;
            }
        }
    } else {  // A2 rows
        int n = (bid - 336) * 256 + t;
        float En[16];
#pragma unroll
        for (int d = 0; d < 16; ++d) En[d] = NE[n * 16 + d];
        float dg[3];
#pragma unroll
        for (int k = 0; k < 3; ++k) dg[k] = adj[k * 1024 * 1024 + n * 1024 + n];
        short row[64];
#pragma unroll
        for (int d = 0; d < 16; ++d) row[d] = f2bf(En[d]);
#pragma unroll
        for (int d = 0; d < 16; ++d)
#pragma unroll
            for (int k = 0; k < 3; ++k) row[16 + d * 3 + k] = f2bf(En[d] * dg[k]);
        short* dst = A2 + n * 64;
#pragma unroll
        for (int q = 0; q < 8; ++q) {
            short8 v;
#pragma unroll
            for (int e2 = 0; e2 < 8; ++e2) v[e2] = row[q * 8 + e2];
            *reinterpret_cast<short8*>(dst + q * 8) = v;
        }
    }
}

// ---------------- gemm1: Y1[n][j=b*64+c] = S @ x[b]; grid (8 n-tiles, 64 b) ----------------
__global__ __launch_bounds__(256) void k_gemm1(const short* __restrict__ S,
                                               const float* __restrict__ x,
                                               short* __restrict__ Y1) {
    __shared__ __align__(16) short As[128 * 64];
    __shared__ __align__(16) short Bs[64 * 64];
    int bx = blockIdx.x, b = blockIdx.y, t = threadIdx.x;
    int wid = t >> 6, lane = t & 63;
    int rsub = lane >> 3, csub = (lane & 7) * 8;
    int wm = wid & 1, wn = wid >> 1;
    int lr = lane & 15, lg = lane >> 4;
    const short* A = S + (size_t)bx * 131072;
    const float* xb = x + (size_t)b * 65536;
    int bm = t >> 2, bc = (t & 3) * 16;
    f32x4 acc[4][2] = {};
    for (int kt = 0; kt < 16; ++kt) {
#pragma unroll
        for (int q = 0; q < 4; ++q) {
            int row = q * 32 + wid * 8;
            gload16(A + (size_t)(row + rsub) * 1024 + kt * 64 + csub, As + row * 64);
        }
#pragma unroll
        for (int j = 0; j < 4; ++j) {
            float4 f = *reinterpret_cast<const float4*>(&xb[(kt * 64 + bm) * 64 + bc + 4 * j]);
            float vv[4] = {f.x, f.y, f.z, f.w};
#pragma unroll
            for (int e = 0; e < 4; ++e) {
                int c = bc + 4 * j + e;
                Bs[c * 64 + (bm ^ swz(c))] = f2bf(vv[e]);
            }
        }
        __syncthreads();
#pragma unroll
        for (int ks = 0; ks < 2; ++ks) {
            int kk = ks * 32 + lg * 8;
            short8 af[4], bfr[2];
#pragma unroll
            for (int i = 0; i < 4; ++i)
                af[i] = *reinterpret_cast<const short8*>(&As[(wm * 64 + i * 16 + lr) * 64 + kk]);
#pragma unroll
            for (int nf = 0; nf < 2; ++nf) {
                int c = wn * 32 + nf * 16 + lr;
                bfr[nf] = *reinterpret_cast<const short8*>(&Bs[c * 64 + (kk ^ swz(c))]);
            }
#pragma unroll
            for (int i = 0; i < 4; ++i)
#pragma unroll
                for (int nf = 0; nf < 2; ++nf)
                    acc[i][nf] = mfma16(af[i], bfr[nf], acc[i][nf]);
        }
        __syncthreads();
    }
#pragma unroll
    for (int i = 0; i < 4; ++i)
#pragma unroll
        for (int nf = 0; nf < 2; ++nf)
#pragma unroll
            for (int r = 0; r < 4; ++r) {
                int g = wm * 64 + i * 16 + lg * 4 + r;
                int c = wn * 32 + nf * 16 + lr;
                Y1[(size_t)(bx * 128 + g) * 4096 + b * 64 + c] = f2bf(acc[i][nf][r]);
            }
}

// ---------------- gemm2: Y2[n][j] = S @ y1[b] (y1 read from [n][j]); grid (8, 64) ----------------
__global__ __launch_bounds__(256) void k_gemm2(const short* __restrict__ S,
                                               const short* __restrict__ Y1,
                                               short* __restrict__ Y2) {
    __shared__ __align__(16) short As[128 * 64];
    __shared__ __align__(16) short Bs[64 * 64];
    int bx = blockIdx.x, b = blockIdx.y, t = threadIdx.x;
    int wid = t >> 6, lane = t & 63;
    int rsub = lane >> 3, csub = (lane & 7) * 8;
    int wm = wid & 1, wn = wid >> 1;
    int lr = lane & 15, lg = lane >> 4;
    const short* A = S + (size_t)bx * 131072;
    int bm = t >> 3, bc0 = (t & 7) * 8;
    f32x4 acc[4][2] = {};
    for (int kt = 0; kt < 16; ++kt) {
#pragma unroll
        for (int q = 0; q < 4; ++q) {
            int row = q * 32 + wid * 8;
            gload16(A + (size_t)(row + rsub) * 1024 + kt * 64 + csub, As + row * 64);
        }
#pragma unroll
        for (int it = 0; it < 2; ++it) {
            int m = bm + 32 * it;
            short8 hv = *reinterpret_cast<const short8*>(
                &Y1[(size_t)(kt * 64 + m) * 4096 + b * 64 + bc0]);
#pragma unroll
            for (int j = 0; j < 8; ++j) {
                int c = bc0 + j;
                Bs[c * 64 + (m ^ swz(c))] = hv[j];
            }
        }
        __syncthreads();
#pragma unroll
        for (int ks = 0; ks < 2; ++ks) {
            int kk = ks * 32 + lg * 8;
            short8 af[4], bfr[2];
#pragma unroll
            for (int i = 0; i < 4; ++i)
                af[i] = *reinterpret_cast<const short8*>(&As[(wm * 64 + i * 16 + lr) * 64 + kk]);
#pragma unroll
            for (int nf = 0; nf < 2; ++nf) {
                int c = wn * 32 + nf * 16 + lr;
                bfr[nf] = *reinterpret_cast<const short8*>(&Bs[c * 64 + (kk ^ swz(c))]);
            }
#pragma unroll
            for (int i = 0; i < 4; ++i)
#pragma unroll
                for (int nf = 0; nf < 2; ++nf)
                    acc[i][nf] = mfma16(af[i], bfr[nf], acc[i][nf]);
        }
        __syncthreads();
    }
#pragma unroll
    for (int i = 0; i < 4; ++i)
#pragma unroll
        for (int nf = 0; nf < 2; ++nf)
#pragma unroll
            for (int r = 0; r < 4; ++r) {
                int g = wm * 64 + i * 16 + lg * 4 + r;
                int c = wn * 32 + nf * 16 + lr;
                Y2[(size_t)(bx * 128 + g) * 4096 + b * 64 + c] = f2bf(acc[i][nf][r]);
            }
}

// ---------------- Wall = A2 @ B2^T, fragment-interleaved; spare blocks: xs finalize ----------------
// Wall[n*16384 + (j>>3)*512 + o*8 + (j&7)]  (j = epi-k 0..255, o = 0..63)
__global__ __launch_bounds__(256) void k_gemm_w(const short* __restrict__ A2,
                                                const short* __restrict__ B2,
                                                short* __restrict__ Wall,
                                                const float* __restrict__ xsp,
                                                short* __restrict__ xs_bf) {
    int bx = blockIdx.x, by = blockIdx.y, t = threadIdx.x;
    if (bx == 128) {  // xs finalize: 8 blocks x 512 = 4096 outputs
#pragma unroll
        for (int p = 0; p < 2; ++p) {
            int j = by * 512 + p * 256 + t;
            int b = j >> 6, c = j & 63;
            float s = xsp[(b * 4 + 0) * 64 + c] + xsp[(b * 4 + 1) * 64 + c] +
                      xsp[(b * 4 + 2) * 64 + c] + xsp[(b * 4 + 3) * 64 + c];
            xs_bf[j] = f2bf(s);
        }
        return;
    }
    __shared__ __align__(16) short As[128 * 64];
    __shared__ __align__(16) short Bs[128 * 64];
#pragma unroll
    for (int i = 0; i < 4; ++i) {
        int slot = t + 256 * i;
        int row = slot >> 3, k8 = slot & 7;
        int sw = swz(row);
        short8 va = *reinterpret_cast<const short8*>(A2 + (by * 128 + row) * 64 + k8 * 8);
        *reinterpret_cast<short8*>(&As[row * 64 + ((k8 * 8) ^ sw)]) = va;
        short8 vb = *reinterpret_cast<const short8*>(B2 + (bx * 128 + row) * 64 + k8 * 8);
        *reinterpret_cast<short8*>(&Bs[row * 64 + ((k8 * 8) ^ sw)]) = vb;
    }
    __syncthreads();
    int w = t >> 6, l = t & 63;
    int wm = w & 1, wn = w >> 1;
    int lr = l & 15, lg = l >> 4;
    f32x4 acc[4][4] = {};
#pragma unroll
    for (int ks = 0; ks < 2; ++ks) {
        int kk = ks * 32 + lg * 8;
        short8 af[4], bfr[4];
#pragma unroll
        for (int mf = 0; mf < 4; ++mf) {
            int row = wm * 64 + mf * 16 + lr;
            af[mf] = *reinterpret_cast<const short8*>(&As[row * 64 + (kk ^ swz(row))]);
        }
#pragma unroll
        for (int nf = 0; nf < 4; ++nf) {
            int row = wn * 64 + nf * 16 + lr;
            bfr[nf] = *reinterpret_cast<const short8*>(&Bs[row * 64 + (kk ^ swz(row))]);
        }
#pragma unroll
        for (int mf = 0; mf < 4; ++mf)
#pragma unroll
            for (int nf = 0; nf < 4; ++nf)
                acc[mf][nf] = mfma16(af[mf], bfr[nf], acc[mf][nf]);
    }
#pragma unroll
    for (int mf = 0; mf < 4; ++mf)
#pragma unroll
        for (int nf = 0; nf < 4; ++nf)
#pragma unroll
            for (int r = 0; r < 4; ++r) {
                int row = by * 128 + wm * 64 + mf * 16 + lg * 4 + r;
                int col = bx * 128 + wn * 64 + nf * 16 + lr;
                int o = col >> 8, j = col & 255;
                Wall[(size_t)row * 16384 + (size_t)(j >> 3) * 512 + o * 8 + (j & 7)] =
                    f2bf(acc[mf][nf][r]);
            }
}

// ---------------- epilogue: r4's streaming per-node MFMA (M=64 b, N=64 o, K=256) ----------------
__global__ __launch_bounds__(256) void k_epi(
        const float* __restrict__ x, const short* __restrict__ Y1,
        const short* __restrict__ Y2, const short* __restrict__ xs_bf,
        const float* __restrict__ s_bn, const short* __restrict__ Wall,
        const float* __restrict__ NE, const float* __restrict__ bp,
        const float* __restrict__ wwin, float* __restrict__ out) {
    int n = blockIdx.x, t = threadIdx.x;
    __shared__ __align__(16) short xst[64 * 64];
    __shared__ float E_l[16];
    __shared__ float bias_l[192];
    __shared__ float ww_l[64];
    __shared__ float sq_l[2][2][64];
    __shared__ float wwn_l;
    if (t < 16) E_l[t] = NE[n * 16 + t];
    __syncthreads();
    if (t < 192) {
        float s = 0.f;
#pragma unroll
        for (int d = 0; d < 16; ++d) s += E_l[d] * bp[d * 192 + t];
        bias_l[t] = s;
    } else {
        int o = t - 192;
        float s = 0.f;
#pragma unroll
        for (int d = 0; d < 16; ++d) s += E_l[d] * wwin[d * 64 + o];
        ww_l[o] = s;
    }
    // stage xs tile (swizzled)
#pragma unroll
    for (int p = 0; p < 2; ++p) {
        int idx = t + 256 * p;
        int b = idx >> 3, q = idx & 7;
        short8 v = *reinterpret_cast<const short8*>(&xs_bf[b * 64 + q * 8]);
        *reinterpret_cast<short8*>(&xst[b * 64 + ((q * 8) ^ swz(b))]) = v;
    }
    __syncthreads();
    if (t < 64) {  // ||ww||
        float v = ww_l[t];
        float s2 = v * v;
#pragma unroll
        for (int off = 32; off; off >>= 1) s2 += __shfl_xor(s2, off);
        if (t == 0) wwn_l = sqrtf(s2);
    }
    int w = t >> 6, l = t & 63;
    int wm = w & 1, wn = w >> 1;
    int lr = l & 15, lg = l >> 4;
    f32x4 accg[2][2] = {};
    f32x4 acca[2][2] = {};
#pragma unroll
    for (int ks = 0; ks < 8; ++ks) {
        short8 af[2];
#pragma unroll
        for (int mf = 0; mf < 2; ++mf) {
            int b = wm * 32 + mf * 16 + lr;
            int k0 = ks * 32 + lg * 8;
            if (ks < 2) {  // x direct (f32 -> bf16)
                const float4* p =
                    reinterpret_cast<const float4*>(&x[((size_t)b * 1024 + n) * 64 + k0]);
                float4 p0 = p[0], p1 = p[1];
                short8 v;
                v[0] = f2bf(p0.x); v[1] = f2bf(p0.y); v[2] = f2bf(p0.z); v[3] = f2bf(p0.w);
                v[4] = f2bf(p1.x); v[5] = f2bf(p1.y); v[6] = f2bf(p1.z); v[7] = f2bf(p1.w);
                af[mf] = v;
            } else if (ks < 4) {  // y1 from [n][j] (coalesced within the wave)
                af[mf] = *reinterpret_cast<const short8*>(
                    &Y1[(size_t)n * 4096 + b * 64 + (k0 - 64)]);
            } else if (ks < 6) {  // y2
                af[mf] = *reinterpret_cast<const short8*>(
                    &Y2[(size_t)n * 4096 + b * 64 + (k0 - 128)]);
            } else {  // xs from LDS
                af[mf] = *reinterpret_cast<const short8*>(
                    &xst[b * 64 + ((k0 - 192) ^ swz(b))]);
            }
        }
        short8 wfk[2];
#pragma unroll
        for (int nf = 0; nf < 2; ++nf) {
            int o = wn * 32 + nf * 16 + lr;
            wfk[nf] = *reinterpret_cast<const short8*>(
                &Wall[(size_t)n * 16384 + (size_t)(ks * 4 + lg) * 512 + o * 8]);
        }
#pragma unroll
        for (int mf = 0; mf < 2; ++mf)
#pragma unroll
            for (int nf = 0; nf < 2; ++nf) {
                if (ks < 6) accg[mf][nf] = mfma16(af[mf], wfk[nf], accg[mf][nf]);
                else        acca[mf][nf] = mfma16(af[mf], wfk[nf], acca[mf][nf]);
            }
    }
#pragma unroll
    for (int mf = 0; mf < 2; ++mf)
#pragma unroll
        for (int r = 0; r < 4; ++r) {
            float sg = accg[mf][0][r] * accg[mf][0][r] + accg[mf][1][r] * accg[mf][1][r];
            float sa = acca[mf][0][r] * acca[mf][0][r] + acca[mf][1][r] * acca[mf][1][r];
#pragma unroll
            for (int off = 1; off < 16; off <<= 1) {
                sg += __shfl_xor(sg, off);
                sa += __shfl_xor(sa, off);
            }
            if (lr == 0) {
                int b = wm * 32 + mf * 16 + lg * 4 + r;
                sq_l[0][wn][b] = sg;
                sq_l[1][wn][b] = sa;
            }
        }
    __syncthreads();
#pragma unroll
    for (int mf = 0; mf < 2; ++mf)
#pragma unroll
        for (int r = 0; r < 4; ++r) {
            int b = wm * 32 + mf * 16 + lg * 4 + r;
            float ig = 1.f / fmaxf(sqrtf(sq_l[0][0][b] + sq_l[0][1][b]), 1e-12f);
            float ia = 1.f / fmaxf(sqrtf(sq_l[1][0][b] + sq_l[1][1][b]), 1e-12f);
            float* po = out + ((size_t)b * 1024 + n) * 192;
#pragma unroll
            for (int nf = 0; nf < 2; ++nf) {
                int o = wn * 32 + nf * 16 + lr;
                po[o]      = accg[mf][nf][r] * ig + bias_l[o];
                po[64 + o] = acca[mf][nf][r] * ia + bias_l[64 + o];
            }
        }
    // wconv
    float wwn = wwn_l;
#pragma unroll
    for (int it = 0; it < 16; ++it) {
        int b = it * 4 + (t >> 6);
        int o = t & 63;
        float s = s_bn[b * 1024 + n];
        float pre = s * ww_l[o];
        float nrm = fabsf(s) * wwn;
        out[((size_t)b * 1024 + n) * 192 + 128 + o] = pre / fmaxf(nrm, 1e-12f) + bias_l[128 + o];
    }
}

extern "C" void kernel_launch(void* const* d_in, const int* in_sizes, int n_in,
                              void* d_out, int out_size, void* d_ws, size_t ws_size,
                              hipStream_t stream) {
    const float* x    = (const float*)d_in[0];
    const float* xw   = (const float*)d_in[1];
    const float* NE   = (const float*)d_in[2];
    const float* adj  = (const float*)d_in[4];
    const float* wp   = (const float*)d_in[5];
    const float* wpa  = (const float*)d_in[6];
    const float* wwin = (const float*)d_in[7];
    const float* bp   = (const float*)d_in[8];
    const float* Tp   = (const float*)d_in[9];
    float* out = (float*)d_out;

    char* ws = (char*)d_ws;
    const size_t OFF_S    = 0;           // 2 MB
    const size_t OFF_Y1   = 2097152;     // 8 MB
    const size_t OFF_Y2   = 10485760;    // 8 MB
    const size_t OFF_WALL = 18874368;    // 32 MB
    const size_t OFF_A2   = 52428800;    // 128 KB
    const size_t OFF_B2   = 52559872;    // 2 MB
    const size_t OFF_XSP  = 54657024;    // 64 KB
    const size_t OFF_XSBF = 54722560;    // 8 KB
    const size_t OFF_SBN  = 54730752;    // 256 KB
    const size_t NEED     = 54992896;
    if (ws_size < NEED) return;  // fails validation loudly

    short* S     = (short*)(ws + OFF_S);
    short* Y1    = (short*)(ws + OFF_Y1);
    short* Y2    = (short*)(ws + OFF_Y2);
    short* Wall  = (short*)(ws + OFF_WALL);
    short* A2    = (short*)(ws + OFF_A2);
    short* B2    = (short*)(ws + OFF_B2);
    float* xsp   = (float*)(ws + OFF_XSP);
    short* xs_bf = (short*)(ws + OFF_XSBF);
    float* s_bn  = (float*)(ws + OFF_SBN);

    k_supports<<<1024, 256, 0, stream>>>(NE, S);
    k_small<<<340, 256, 0, stream>>>(x, xw, NE, adj, wp, wpa, Tp, B2, A2, xsp, s_bn);
    k_gemm1<<<dim3(8, 64), 256, 0, stream>>>(S, x, Y1);
    k_gemm2<<<dim3(8, 64), 256, 0, stream>>>(S, Y1, Y2);
    k_gemm_w<<<dim3(129, 8), 256, 0, stream>>>(A2, B2, Wall, xsp, xs_bf);
    k_epi<<<1024, 256, 0, stream>>>(x, Y1, Y2, xs_bf, s_bn, Wall, NE, bp, wwin, out);
}